// Round 9
// baseline (166.207 us; speedup 1.0000x reference)
//
#include <hip/hip_runtime.h>
#include <hip/hip_bf16.h>

typedef unsigned short u16;
typedef __attribute__((ext_vector_type(8))) short short8v;   // 8 bf16 (4 VGPR)
typedef __attribute__((ext_vector_type(4))) float float4v;   // 4 f32 acc

__device__ inline u16 f2b(float f) {
  __hip_bfloat16 h = __float2bfloat16(f);
  union { __hip_bfloat16 h; u16 s; } u;
  u.h = h;
  return u.s;
}

__device__ inline float b2f(u16 s) {
  union { u16 s[2]; float f; } u;
  u.s[0] = 0; u.s[1] = s;
  return u.f;
}

__device__ inline void gload_lds16(const u16* g, u16* l) {
  __builtin_amdgcn_global_load_lds(
      (const __attribute__((address_space(1))) void*)g,
      (__attribute__((address_space(3))) void*)l, 16, 0, 0);
}

// ---------------------------------------------------------------------------
// fp32 -> bf16 conversion (vectorized, grid-stride)
// ---------------------------------------------------------------------------
__global__ __launch_bounds__(256) void cvt_f32_bf16(const float* __restrict__ in,
                                                    u16* __restrict__ out, int n4) {
  for (int i = blockIdx.x * blockDim.x + threadIdx.x; i < n4;
       i += gridDim.x * blockDim.x) {
    float4 v = ((const float4*)in)[i];
    ushort4 o;
    o.x = f2b(v.x); o.y = f2b(v.y); o.z = f2b(v.z); o.w = f2b(v.w);
    ((ushort4*)out)[i] = o;
  }
}

// fused 3-matrix weight conversion (one dispatch instead of three)
__global__ __launch_bounds__(256)
void cvt_w3(const float* __restrict__ wa, const float* __restrict__ wb,
            const float* __restrict__ wc, u16* __restrict__ oa,
            u16* __restrict__ ob, u16* __restrict__ oc, int n4each) {
  int i = blockIdx.x * blockDim.x + threadIdx.x;
  const float* src; u16* dst; int off;
  if (i < n4each)            { src = wa; dst = oa; off = i; }
  else if (i < 2 * n4each)   { src = wb; dst = ob; off = i - n4each; }
  else                       { src = wc; dst = oc; off = i - 2 * n4each; }
  float4 v = ((const float4*)src)[off];
  ushort4 o;
  o.x = f2b(v.x); o.y = f2b(v.y); o.z = f2b(v.z); o.w = f2b(v.w);
  ((ushort4*)dst)[off] = o;
}

// ---------------------------------------------------------------------------
// gemm9: m201-style 8-phase 256x256 GEMM. C[m][n] = sum_k A[m][k]*B[n][k].
// BK=64, 512 thr = 8 waves (2M x 4N), per-wave 128x64, acc[8][4].
// LDS 128 KiB = 2 dbuf x {A-Kh0, A-Kh1, B-Kh0, B-Kh1}, each 256r x 32k bf16.
// Phase (ks,mh): 8 ds_read_b128 (B reused at mh1) | stage 1 half-unit ->
// barrier -> lgkm(0)+sched_barrier -> setprio 16 MFMA -> [vmcnt(4) @ g4,g8]
// -> barrier. Stage stream (ledger-verified, units land 5-6 phases ahead):
//   g1:A1(t1)->b1  g2:B1(t1)->b1  g3:A0(t+2)->b0  g4:B0(t+2)->b0 +vm
//   g5:A1(t+2)->b0 g6:B1(t+2)->b0 g7:A0(t+3)->b1  g8:B0(t+3)->b1 +vm
// WAR: every staged region's last read is >=1 barrier earlier. RAW: vmcnt(4)
// leaves only the 2 most recent units in flight; all older landed.
// Swizzle (64B rows, 4 slots): phys slot = s ^ ((row>>1)&3) -> 2-way free.
// REQUIRES nk even, nk >= 2.  MODE: 0 none; 1 skip tile if n0 > m0+256.
// ---------------------------------------------------------------------------
template <int MODE, typename CT>
__global__ __launch_bounds__(512, 1)
void gemm9(const u16* __restrict__ A, int lda, long sA,
           const u16* __restrict__ B, int ldb, long sB,
           CT* __restrict__ C, int ldc, long sC, int K) {
  __shared__ __align__(16) u16 lds[65536];         // 128 KiB

  const int z = blockIdx.z;
  A += (long)z * sA;
  B += (long)z * sB;

  const int m0 = blockIdx.x * 256;
  const int n0 = blockIdx.y * 256;
  if (MODE == 1 && n0 > m0 + 256) return;          // fully masked tile
  const int nk = K >> 6;                           // even by construction

  const int tid  = threadIdx.x;
  const int lane = tid & 63;
  const int wid  = tid >> 6;
  const int wr   = wid >> 2;                       // 0..1 (M)
  const int wc   = wid & 3;                        // 0..3 (N)

  // staging: per K-half unit = 256r x 32k = 1024 chunks of 16B; 2/thread.
  // chunk c: row r=c>>2, phys slot p=c&3 holds logical slot l=p^((r>>1)&3).
  const u16* gA[2]; const u16* gB[2]; int lof[2];
#pragma unroll
  for (int j = 0; j < 2; ++j) {
    int c = tid + j * 512;
    int r = c >> 2;
    int l = (c & 3) ^ ((r >> 1) & 3);
    gA[j] = A + (long)(m0 + r) * lda + l * 8;
    gB[j] = B + (long)(n0 + r) * ldb + l * 8;
    lof[j] = c * 8;                                // u16 offset in region
  }

// stage one half-unit: tile T_, K-half KH_, matrix MAT_ (0=A,1=B), dbuf D_
#define STAGE_U(T_, KH_, MAT_, D_)                                          \
  {                                                                         \
    u16* dst_ = lds + (D_) * 32768 + ((MAT_) * 2 + (KH_)) * 8192;           \
    _Pragma("unroll")                                                       \
    for (int j = 0; j < 2; ++j)                                             \
      gload_lds16(((MAT_) ? gB[j] : gA[j]) + (long)(T_) * 64 + (KH_) * 32,  \
                  dst_ + lof[j]);                                           \
  }

  // ds_read offsets (bytes, region-local), swizzled
  const int swzt = 16 * ((lane >> 4) ^ ((lane >> 1) & 3));
  const int aoff = (wr * 128 + (lane & 15)) * 64 + swzt;
  const int boff = (wc * 64 + (lane & 15)) * 64 + swzt;
  const char* ldsc = (const char*)lds;

  float4v acc[8][4];
#pragma unroll
  for (int i = 0; i < 8; ++i)
#pragma unroll
    for (int j = 0; j < 4; ++j)
      acc[i][j] = (float4v){0.f, 0.f, 0.f, 0.f};

  short8v b_[4];

#define PHASE(D_, KS_, MH_, READB_, STAGE_STMT_, VM_)                       \
  {                                                                         \
    const char* ab_ = ldsc + (D_) * 65536 + (KS_) * 16384;                  \
    const char* bb_ = ldsc + (D_) * 65536 + 32768 + (KS_) * 16384;          \
    short8v a_[4];                                                          \
    _Pragma("unroll")                                                       \
    for (int mi = 0; mi < 4; ++mi)                                          \
      a_[mi] = *(const short8v*)(ab_ + aoff + (MH_) * 4096 + mi * 1024);    \
    if (READB_) {                                                           \
      _Pragma("unroll")                                                     \
      for (int ni = 0; ni < 4; ++ni)                                        \
        b_[ni] = *(const short8v*)(bb_ + boff + ni * 1024);                 \
    }                                                                       \
    STAGE_STMT_;                                                            \
    __builtin_amdgcn_s_barrier();                                           \
    asm volatile("s_waitcnt lgkmcnt(0)" ::: "memory");                      \
    __builtin_amdgcn_sched_barrier(0);                                      \
    __builtin_amdgcn_s_setprio(1);                                          \
    _Pragma("unroll")                                                       \
    for (int mi = 0; mi < 4; ++mi)                                          \
      _Pragma("unroll")                                                     \
      for (int ni = 0; ni < 4; ++ni)                                        \
        acc[(MH_) * 4 + mi][ni] = __builtin_amdgcn_mfma_f32_16x16x32_bf16(  \
            a_[mi], b_[ni], acc[(MH_) * 4 + mi][ni], 0, 0, 0);              \
    __builtin_amdgcn_s_setprio(0);                                          \
    if (VM_) asm volatile("s_waitcnt vmcnt(4)" ::: "memory");               \
    __builtin_amdgcn_s_barrier();                                           \
  }

  // prologue: tile0 all 4 units -> buf0; tile1 A0,B0 -> buf1
  STAGE_U(0, 0, 0, 0); STAGE_U(0, 0, 1, 0);
  STAGE_U(0, 1, 0, 0); STAGE_U(0, 1, 1, 0);
  STAGE_U(1, 0, 0, 1); STAGE_U(1, 0, 1, 1);
  asm volatile("s_waitcnt vmcnt(4)" ::: "memory");  // tile0 fully landed
  __builtin_amdgcn_s_barrier();

  for (int it = 0; it < (nk >> 1); ++it) {
    const int t0 = 2 * it, t1 = 2 * it + 1;
    const bool s2 = (t0 + 2 < nk), s3 = (t1 + 2 < nk);
    PHASE(0, 0, 0, true,  { STAGE_U(t1, 1, 0, 1); },           false);  // g1
    PHASE(0, 0, 1, false, { STAGE_U(t1, 1, 1, 1); },           false);  // g2
    PHASE(0, 1, 0, true,  { if (s2) STAGE_U(t0 + 2, 0, 0, 0); }, false);// g3
    PHASE(0, 1, 1, false, { if (s2) STAGE_U(t0 + 2, 0, 1, 0); }, true); // g4
    PHASE(1, 0, 0, true,  { if (s2) STAGE_U(t0 + 2, 1, 0, 0); }, false);// g5
    PHASE(1, 0, 1, false, { if (s2) STAGE_U(t0 + 2, 1, 1, 0); }, false);// g6
    PHASE(1, 1, 0, true,  { if (s3) STAGE_U(t1 + 2, 0, 0, 1); }, false);// g7
    PHASE(1, 1, 1, false, { if (s3) STAGE_U(t1 + 2, 0, 1, 1); }, true); // g8
  }
#undef PHASE
#undef STAGE_U

  // epilogue: C/D layout col = lane&15, row = (lane>>4)*4 + reg
  CT* c = C + (long)z * sC;
  const int r0base = m0 + wr * 128 + ((lane >> 4) << 2);
  const int cbase  = n0 + wc * 64 + (lane & 15);
#pragma unroll
  for (int mi = 0; mi < 8; ++mi) {
#pragma unroll
    for (int ni = 0; ni < 4; ++ni) {
      const int r0 = r0base + mi * 16;
      const int cc = cbase + ni * 16;
#pragma unroll
      for (int r = 0; r < 4; ++r) {
        float v = acc[mi][ni][r];
        if constexpr (__is_same(CT, float)) c[(long)(r0 + r) * ldc + cc] = v;
        else                                c[(long)(r0 + r) * ldc + cc] = f2b(v);
      }
    }
  }
}

// ---------------------------------------------------------------------------
// gemm8 (r8-validated): 128x128 tile, BK=64, 4 waves, 2 bufs, 2 blocks/CU.
// Used for vt (small M) and PV (odd/variable nk).
// ---------------------------------------------------------------------------
template <int MODE, typename CT>
__global__ __launch_bounds__(256, 2)
void gemm8(const u16* __restrict__ A, int lda, long sA,
           const u16* __restrict__ B, int ldb, long sB,
           CT* __restrict__ C, int ldc, long sC, int K) {
  constexpr int BM = 128, BN = 128;
  constexpr int A_U16 = BM * 64;                  // 8192
  constexpr int TILE_U16 = (BM + BN) * 64;        // 16384
  constexpr int TILE_BYTES = TILE_U16 * 2;        // 32768
  __shared__ __align__(16) u16 lds[2 * TILE_U16]; // 64 KiB

  const int z = blockIdx.z;
  A += (long)z * sA;
  B += (long)z * sB;

  int bx = blockIdx.x;
  if (MODE == 2) bx = gridDim.x - 1 - bx;         // heavy tiles first
  const int m0 = bx * BM;
  const int n0 = blockIdx.y * BN;
  if (MODE == 1 && n0 > m0 + BM) return;          // fully masked tile
  int Keff = K;
  if (MODE == 2) Keff = min(m0 + BM + 1, K);
  const int nk = (Keff + 63) >> 6;

  const int tid  = threadIdx.x;
  const int lane = tid & 63;
  const int wid  = tid >> 6;
  const int wr   = wid >> 1;
  const int wc   = wid & 1;

  const u16* gsrc[8];
  int loff[8];
#pragma unroll
  for (int j = 0; j < 4; ++j) {
    int c = tid + j * 256;
    int r = c >> 3;
    int kg = ((c & 7) ^ (r & 7)) * 8;
    gsrc[j] = A + (long)(m0 + r) * lda + kg;
    loff[j] = c * 8;
  }
#pragma unroll
  for (int j = 0; j < 4; ++j) {
    int c = tid + j * 256;
    int r = c >> 3;
    int kg = ((c & 7) ^ (r & 7)) * 8;
    gsrc[4 + j] = B + (long)(n0 + r) * ldb + kg;
    loff[4 + j] = A_U16 + c * 8;
  }

#define STAGE_ALL(T_, DST_)                                                 \
  {                                                                         \
    _Pragma("unroll")                                                       \
    for (int s = 0; s < 8; ++s)                                             \
      gload_lds16(gsrc[s] + (long)(T_) * 64, (DST_) + loff[s]);             \
  }

  const int kl  = (lane >> 4) * 16;
  const int swz = (lane & 7) << 4;
  const int kx0 = kl ^ swz;
  const int kx1 = (64 + kl) ^ swz;
  const int abase = (wr * 64 + (lane & 15)) * 128;
  const int bbase = 2 * A_U16 + (wc * 64 + (lane & 15)) * 128;

  float4v acc[4][4];
#pragma unroll
  for (int i = 0; i < 4; ++i)
#pragma unroll
    for (int j = 0; j < 4; ++j)
      acc[i][j] = (float4v){0.f, 0.f, 0.f, 0.f};

  STAGE_ALL(0, lds);
  asm volatile("s_waitcnt vmcnt(0)" ::: "memory");
  __builtin_amdgcn_s_barrier();

  for (int t = 0; t < nk; ++t) {
    const char* bb = (const char*)lds + (t & 1) * TILE_BYTES;
    u16* sb = lds + ((t & 1) ^ 1) * TILE_U16;

    if (t + 1 < nk) STAGE_ALL(t + 1, sb);

    short8v a0[4], b0[4], a1[4], b1[4];
#pragma unroll
    for (int mi = 0; mi < 4; ++mi)
      a0[mi] = *(const short8v*)(bb + abase + mi * 2048 + kx0);
#pragma unroll
    for (int ni = 0; ni < 4; ++ni)
      b0[ni] = *(const short8v*)(bb + bbase + ni * 2048 + kx0);
    __builtin_amdgcn_sched_barrier(0);
#pragma unroll
    for (int mi = 0; mi < 4; ++mi)
      a1[mi] = *(const short8v*)(bb + abase + mi * 2048 + kx1);
#pragma unroll
    for (int ni = 0; ni < 4; ++ni)
      b1[ni] = *(const short8v*)(bb + bbase + ni * 2048 + kx1);

    asm volatile("s_waitcnt lgkmcnt(8)" ::: "memory");
    __builtin_amdgcn_sched_barrier(0);
    __builtin_amdgcn_s_setprio(1);
#pragma unroll
    for (int mi = 0; mi < 4; ++mi)
#pragma unroll
      for (int ni = 0; ni < 4; ++ni)
        acc[mi][ni] = __builtin_amdgcn_mfma_f32_16x16x32_bf16(
            a0[mi], b0[ni], acc[mi][ni], 0, 0, 0);
    __builtin_amdgcn_s_setprio(0);

    asm volatile("s_waitcnt lgkmcnt(0)" ::: "memory");
    __builtin_amdgcn_sched_barrier(0);
    __builtin_amdgcn_s_setprio(1);
#pragma unroll
    for (int mi = 0; mi < 4; ++mi)
#pragma unroll
      for (int ni = 0; ni < 4; ++ni)
        acc[mi][ni] = __builtin_amdgcn_mfma_f32_16x16x32_bf16(
            a1[mi], b1[ni], acc[mi][ni], 0, 0, 0);
    __builtin_amdgcn_s_setprio(0);

    asm volatile("s_waitcnt vmcnt(0)" ::: "memory");
    __builtin_amdgcn_s_barrier();
  }
#undef STAGE_ALL

  CT* c = C + (long)z * sC;
  const int r0base = m0 + wr * 64 + ((lane >> 4) << 2);
  const int cbase  = n0 + wc * 64 + (lane & 15);
#pragma unroll
  for (int mi = 0; mi < 4; ++mi) {
#pragma unroll
    for (int ni = 0; ni < 4; ++ni) {
      const int r0 = r0base + mi * 16;
      const int cc = cbase + ni * 16;
#pragma unroll
      for (int r = 0; r < 4; ++r) {
        float v = acc[mi][ni][r];
        if constexpr (__is_same(CT, float)) c[(long)(r0 + r) * ldc + cc] = v;
        else                                c[(long)(r0 + r) * ldc + cc] = f2b(v);
      }
    }
  }
}

// ---------------------------------------------------------------------------
// masked scaled softmax, in place on bf16 S (one row per block, B*T blocks).
// Row i sees j <= i+1; scale = 1/32. Zero-pads P up to the PV staged extent
// (tile base + 192, BM=128/BK=64).
// ---------------------------------------------------------------------------
__global__ __launch_bounds__(256)
void softmax_kernel(u16* __restrict__ SP, int T) {
  const int  i    = blockIdx.x & (T - 1);
  const long base = (long)blockIdx.x * T;
  const int  nvis = min(i + 2, T);
  const int  capJ = min(T, ((i >> 7) << 7) + 192);  // PV staging extent
  const float scale = 0.03125f;

  __shared__ float red[4];

  const int j0 = threadIdx.x * 8;
  float v[8];
  float m = -INFINITY;
  if (j0 < nvis) {
    short8v raw = *(const short8v*)&SP[base + j0];
#pragma unroll
    for (int e = 0; e < 8; ++e) {
      float f = (j0 + e < nvis) ? b2f((u16)raw[e]) * scale : -INFINITY;
      v[e] = f;
      m = fmaxf(m, f);
    }
  }
#pragma unroll
  for (int o = 32; o; o >>= 1) m = fmaxf(m, __shfl_xor(m, o));
  const int wid = threadIdx.x >> 6;
  if ((threadIdx.x & 63) == 0) red[wid] = m;
  __syncthreads();
  m = fmaxf(fmaxf(red[0], red[1]), fmaxf(red[2], red[3]));
  __syncthreads();

  float s = 0.f;
  if (j0 < nvis) {
#pragma unroll
    for (int e = 0; e < 8; ++e) {
      float p = (j0 + e < nvis) ? __expf(v[e] - m) : 0.f;
      v[e] = p;
      s += p;
    }
  }
#pragma unroll
  for (int o = 32; o; o >>= 1) s += __shfl_xor(s, o);
  if ((threadIdx.x & 63) == 0) red[wid] = s;
  __syncthreads();
  s = red[0] + red[1] + red[2] + red[3];
  const float inv = 1.0f / s;

  if (j0 < capJ) {
    short8v o8;
#pragma unroll
    for (int e = 0; e < 8; ++e)
      o8[e] = (short)f2b((j0 + e < nvis) ? v[e] * inv : 0.f);
    *(short8v*)&SP[base + j0] = o8;
  }
}

// ---------------------------------------------------------------------------
extern "C" void kernel_launch(void* const* d_in, const int* in_sizes, int n_in,
                              void* d_out, int out_size, void* d_ws, size_t ws_size,
                              hipStream_t stream) {
  const float* x  = (const float*)d_in[0];
  const float* Wq = (const float*)d_in[1];
  const float* Wk = (const float*)d_in[2];
  const float* Wv = (const float*)d_in[3];
  float* out = (float*)d_out;

  const int B = 4, T = 2048, D = 1024;
  const int M = B * T;          // 8192
  const long TT = (long)T * T;  // 4 Mi elements

  char* ws = (char*)d_ws;
  u16* qk  = (u16*)(ws);                      // 32 MiB: [8192][2048], q|k
  u16* vt  = (u16*)(ws + (32l << 20));        // 16 MiB: [1024][8192] d-major
  u16* xb  = (u16*)(ws + (48l << 20));        // 16 MiB (dead after vt GEMM)
  u16* wqk = (u16*)(ws + (64l << 20));        //  4 MiB: [2048][1024]
  u16* wv  = (u16*)(ws + (68l << 20));        //  2 MiB
  u16* S   = (u16*)(ws + (48l << 20));        // 32 MiB: 4 x [2048][2048] bf16
                                              //   (overlaps xb/wqk/wv; written
                                              //    only after they are dead)
  // peak: 80 MiB

  // fp32 -> bf16
  cvt_f32_bf16<<<2048, 256, 0, stream>>>(x, xb, (M * D) / 4);
  cvt_w3<<<3 * (D * D / 4) / 256, 256, 0, stream>>>(
      Wq, Wk, Wv, wqk, wqk + (long)D * D, wv, D * D / 4);

  // qk = x @ [Wq;Wk]^T  (8192 x 2048): 8-phase 256^2, grid 32x8 = 256 blocks
  gemm9<0, u16><<<dim3(M / 256, 2 * D / 256, 1), 512, 0, stream>>>(
      xb, D, 0, wqk, D, 0, qk, 2 * D, 0, D);
  // vt = Wv @ x^T  (1024 x 8192, d-major): grid 8x64
  gemm8<0, u16><<<dim3(D / 128, M / 128, 1), 256, 0, stream>>>(
      wv, D, 0, xb, D, 0, vt, M, 0, D);

  // S_b = q_b k_b^T (bf16, tile-skip above diagonal): 8-phase 256^2,
  // grid 8x8x4, 172 live blocks
  gemm9<1, u16><<<dim3(T / 256, T / 256, B), 512, 0, stream>>>(
      qk, 2 * D, (long)T * 2 * D,
      qk + D, 2 * D, (long)T * 2 * D,
      S, T, TT, D);

  // softmax in place (S -> P), all rows of all batches
  softmax_kernel<<<B * T, 256, 0, stream>>>(S, T);

  // O_b = P_b V_b = P_b (vt_b)^T, K capped per tile-row: grid 16x8x4
  gemm8<2, float><<<dim3(T / 128, D / 128, B), 256, 0, stream>>>(
      S, T, TT,
      vt, M, T,
      out, D, (long)T * D, T);
}

// Round 10
// 152.931 us; speedup vs baseline: 1.0868x; 1.0868x over previous
//
#include <hip/hip_runtime.h>
#include <hip/hip_bf16.h>

typedef unsigned short u16;
typedef __attribute__((ext_vector_type(8))) short short8v;   // 8 bf16 (4 VGPR)
typedef __attribute__((ext_vector_type(4))) float float4v;   // 4 f32 acc

__device__ inline u16 f2b(float f) {
  __hip_bfloat16 h = __float2bfloat16(f);
  union { __hip_bfloat16 h; u16 s; } u;
  u.h = h;
  return u.s;
}

__device__ inline float b2f(u16 s) {
  union { u16 s[2]; float f; } u;
  u.s[0] = 0; u.s[1] = s;
  return u.f;
}

__device__ inline void gload_lds16(const u16* g, u16* l) {
  __builtin_amdgcn_global_load_lds(
      (const __attribute__((address_space(1))) void*)g,
      (__attribute__((address_space(3))) void*)l, 16, 0, 0);
}

// ---------------------------------------------------------------------------
// fp32 -> bf16 conversion (vectorized, grid-stride)
// ---------------------------------------------------------------------------
__global__ __launch_bounds__(256) void cvt_f32_bf16(const float* __restrict__ in,
                                                    u16* __restrict__ out, int n4) {
  for (int i = blockIdx.x * blockDim.x + threadIdx.x; i < n4;
       i += gridDim.x * blockDim.x) {
    float4 v = ((const float4*)in)[i];
    ushort4 o;
    o.x = f2b(v.x); o.y = f2b(v.y); o.z = f2b(v.z); o.w = f2b(v.w);
    ((ushort4*)out)[i] = o;
  }
}

// fused 3-matrix weight conversion (one dispatch instead of three)
__global__ __launch_bounds__(256)
void cvt_w3(const float* __restrict__ wa, const float* __restrict__ wb,
            const float* __restrict__ wc, u16* __restrict__ oa,
            u16* __restrict__ ob, u16* __restrict__ oc, int n4each) {
  int i = blockIdx.x * blockDim.x + threadIdx.x;
  const float* src; u16* dst; int off;
  if (i < n4each)            { src = wa; dst = oa; off = i; }
  else if (i < 2 * n4each)   { src = wb; dst = ob; off = i - n4each; }
  else                       { src = wc; dst = oc; off = i - 2 * n4each; }
  float4 v = ((const float4*)src)[off];
  ushort4 o;
  o.x = f2b(v.x); o.y = f2b(v.y); o.z = f2b(v.z); o.w = f2b(v.w);
  ((ushort4*)dst)[off] = o;
}

// ---------------------------------------------------------------------------
// gemm_core (r8-validated loop): C[m][n] = sum_k A[m][k]*B[n][k], both
// row-major K-contiguous. 128x128 tile, BK=64, 4 waves (2x2), 64x64/wave.
// 2-buffer LDS (64 KB -> 2 blocks/CU). Per K-tile: stage(t+1) first ->
// 16 ds_reads in two pinned groups -> lgkmcnt(8) -> 16 MFMA slice0 ->
// lgkmcnt(0) -> 16 MFMA slice1 -> vmcnt(0) -> s_barrier.
// XOR swizzle byte^=(row&7)<<4 via pre-swizzled global source (linear
// global_load_lds dest) + swizzled ds_reads (0 conflicts, verified r3-r9).
// ---------------------------------------------------------------------------
template <typename CT>
__device__ __forceinline__ void gemm_core(
    const u16* __restrict__ A, int lda,
    const u16* __restrict__ B, int ldb,
    CT* __restrict__ C, int ldc, int m0, int n0, int nk) {
  constexpr int A_U16 = 8192;                     // 128 rows x 64 k
  constexpr int TILE_U16 = 16384;
  constexpr int TILE_BYTES = 32768;
  __shared__ __align__(16) u16 lds[2 * TILE_U16]; // 64 KiB

  const int tid  = threadIdx.x;
  const int lane = tid & 63;
  const int wid  = tid >> 6;
  const int wr   = wid >> 1;
  const int wc   = wid & 1;

  // staging map: chunk c -> LDS bytes [16c,16c+16): row r=c>>3, physical
  // 16B slot (c&7) holds logical k-slot (c&7)^(r&7) -> global k-off *8.
  const u16* gsrc[8];
  int loff[8];
#pragma unroll
  for (int j = 0; j < 4; ++j) {
    int c = tid + j * 256;                        // A chunks 0..1023
    int r = c >> 3;
    int kg = ((c & 7) ^ (r & 7)) * 8;
    gsrc[j] = A + (long)(m0 + r) * lda + kg;
    loff[j] = c * 8;
  }
#pragma unroll
  for (int j = 0; j < 4; ++j) {
    int c = tid + j * 256;                        // B chunks 0..1023
    int r = c >> 3;
    int kg = ((c & 7) ^ (r & 7)) * 8;
    gsrc[4 + j] = B + (long)(n0 + r) * ldb + kg;
    loff[4 + j] = A_U16 + c * 8;
  }

#define STAGE_ALL(T_, DST_)                                                 \
  {                                                                         \
    _Pragma("unroll")                                                       \
    for (int s = 0; s < 8; ++s)                                             \
      gload_lds16(gsrc[s] + (long)(T_) * 64, (DST_) + loff[s]);             \
  }

  const int kl  = (lane >> 4) * 16;
  const int swz = (lane & 7) << 4;
  const int kx0 = kl ^ swz;
  const int kx1 = (64 + kl) ^ swz;
  const int abase = (wr * 64 + (lane & 15)) * 128;
  const int bbase = 2 * A_U16 + (wc * 64 + (lane & 15)) * 128;

  float4v acc[4][4];
#pragma unroll
  for (int i = 0; i < 4; ++i)
#pragma unroll
    for (int j = 0; j < 4; ++j)
      acc[i][j] = (float4v){0.f, 0.f, 0.f, 0.f};

  STAGE_ALL(0, lds);
  asm volatile("s_waitcnt vmcnt(0)" ::: "memory");
  __builtin_amdgcn_s_barrier();

  for (int t = 0; t < nk; ++t) {
    const char* bb = (const char*)lds + (t & 1) * TILE_BYTES;
    u16* sb = lds + ((t & 1) ^ 1) * TILE_U16;

    if (t + 1 < nk) STAGE_ALL(t + 1, sb);         // issue early: max slack

    short8v a0[4], b0[4], a1[4], b1[4];
#pragma unroll
    for (int mi = 0; mi < 4; ++mi)
      a0[mi] = *(const short8v*)(bb + abase + mi * 2048 + kx0);
#pragma unroll
    for (int ni = 0; ni < 4; ++ni)
      b0[ni] = *(const short8v*)(bb + bbase + ni * 2048 + kx0);
    __builtin_amdgcn_sched_barrier(0);            // pin group order
#pragma unroll
    for (int mi = 0; mi < 4; ++mi)
      a1[mi] = *(const short8v*)(bb + abase + mi * 2048 + kx1);
#pragma unroll
    for (int ni = 0; ni < 4; ++ni)
      b1[ni] = *(const short8v*)(bb + bbase + ni * 2048 + kx1);

    asm volatile("s_waitcnt lgkmcnt(8)" ::: "memory");  // slice0 landed
    __builtin_amdgcn_sched_barrier(0);
    __builtin_amdgcn_s_setprio(1);
#pragma unroll
    for (int mi = 0; mi < 4; ++mi)
#pragma unroll
      for (int ni = 0; ni < 4; ++ni)
        acc[mi][ni] = __builtin_amdgcn_mfma_f32_16x16x32_bf16(
            a0[mi], b0[ni], acc[mi][ni], 0, 0, 0);
    __builtin_amdgcn_s_setprio(0);

    asm volatile("s_waitcnt lgkmcnt(0)" ::: "memory");  // slice1 landed
    __builtin_amdgcn_sched_barrier(0);
    __builtin_amdgcn_s_setprio(1);
#pragma unroll
    for (int mi = 0; mi < 4; ++mi)
#pragma unroll
      for (int ni = 0; ni < 4; ++ni)
        acc[mi][ni] = __builtin_amdgcn_mfma_f32_16x16x32_bf16(
            a1[mi], b1[ni], acc[mi][ni], 0, 0, 0);
    __builtin_amdgcn_s_setprio(0);

    asm volatile("s_waitcnt vmcnt(0)" ::: "memory");  // t+1's stage landed
    __builtin_amdgcn_s_barrier();                     // visible to all waves
  }
#undef STAGE_ALL

  // epilogue: C/D layout col = lane&15, row = (lane>>4)*4 + reg
  const int r0base = m0 + wr * 64 + ((lane >> 4) << 2);
  const int cbase  = n0 + wc * 64 + (lane & 15);
#pragma unroll
  for (int mi = 0; mi < 4; ++mi) {
#pragma unroll
    for (int ni = 0; ni < 4; ++ni) {
      const int r0 = r0base + mi * 16;
      const int cc = cbase + ni * 16;
#pragma unroll
      for (int r = 0; r < 4; ++r) {
        float v = acc[mi][ni][r];
        if constexpr (__is_same(CT, float)) C[(long)(r0 + r) * ldc + cc] = v;
        else                                C[(long)(r0 + r) * ldc + cc] = f2b(v);
      }
    }
  }
}

// ---------------------------------------------------------------------------
// gemm8 wrapper: MODE 0 = plain (qk); MODE 2 = PV (K cap m0+129; bx reversed
// only for z<2 so CU-paired blocks (stride 256 => z+2, same bx slot) get
// nk(15-x)+nk(x) ~ uniform 35 K-tiles instead of 2*nk(x) in 6..64).
// ---------------------------------------------------------------------------
template <int MODE, typename CT>
__global__ __launch_bounds__(256, 2)
void gemm8(const u16* __restrict__ A, int lda, long sA,
           const u16* __restrict__ B, int ldb, long sB,
           CT* __restrict__ C, int ldc, long sC, int K) {
  const int z = blockIdx.z;
  int bx = blockIdx.x;
  if (MODE == 2 && z < 2) bx = gridDim.x - 1 - bx;   // pair-balanced order
  const int m0 = bx * 128;
  const int n0 = blockIdx.y * 128;
  int Keff = K;
  if (MODE == 2) Keff = min(m0 + 129, K);
  gemm_core<CT>(A + (long)z * sA, lda, B + (long)z * sB, ldb,
                C + (long)z * sC, ldc, m0, n0, (Keff + 63) >> 6);
}

// ---------------------------------------------------------------------------
// merged vt + S dispatch (independent ops, uniform nk=16 blocks):
// bid < 512  : vt = Wv @ x^T  (1024 x 8192 tile grid 8x64)
// bid >= 512 : S_b = q_b k_b^T, tile-skip above diagonal (16x16x4, 604 live)
// 1116 live blocks backfill 512 residency slots continuously (~2.2 rounds)
// vs 1 + 2 quantized rounds separately.
// ---------------------------------------------------------------------------
__global__ __launch_bounds__(256, 2)
void gemm_vts(const u16* __restrict__ xb, const u16* __restrict__ wv,
              const u16* __restrict__ qk, u16* __restrict__ vt,
              u16* __restrict__ S) {
  const int bid = blockIdx.x;
  const u16 *A, *B; u16* C; int lda, ldc, m0, n0;
  if (bid < 512) {
    A = wv; B = xb; C = vt; lda = 1024; ldc = 8192;
    m0 = (bid & 7) * 128; n0 = (bid >> 3) * 128;
  } else {
    const int sid = bid - 512;
    const int z = sid >> 8, r = sid & 255;
    m0 = (r & 15) * 128; n0 = (r >> 4) * 128;
    if (n0 > m0 + 128) return;                     // fully masked tile
    const long zo = (long)z * 4194304;             // z * T * 2D
    A = qk + zo; B = qk + zo + 1024; C = S + zo;
    lda = 2048; ldc = 2048;
  }
  gemm_core<u16>(A, lda, B, lda, C, ldc, m0, n0, 16);
}

// ---------------------------------------------------------------------------
// masked scaled softmax, in place on bf16 S (one row per block, B*T blocks).
// Row i sees j <= i+1; scale = 1/32. Zero-pads P up to the PV staged extent
// (tile base + 192, BM=128/BK=64).
// ---------------------------------------------------------------------------
__global__ __launch_bounds__(256)
void softmax_kernel(u16* __restrict__ SP, int T) {
  const int  i    = blockIdx.x & (T - 1);
  const long base = (long)blockIdx.x * T;
  const int  nvis = min(i + 2, T);
  const int  capJ = min(T, ((i >> 7) << 7) + 192);  // PV staging extent
  const float scale = 0.03125f;

  __shared__ float red[4];

  const int j0 = threadIdx.x * 8;
  float v[8];
  float m = -INFINITY;
  if (j0 < nvis) {
    short8v raw = *(const short8v*)&SP[base + j0];
#pragma unroll
    for (int e = 0; e < 8; ++e) {
      float f = (j0 + e < nvis) ? b2f((u16)raw[e]) * scale : -INFINITY;
      v[e] = f;
      m = fmaxf(m, f);
    }
  }
#pragma unroll
  for (int o = 32; o; o >>= 1) m = fmaxf(m, __shfl_xor(m, o));
  const int wid = threadIdx.x >> 6;
  if ((threadIdx.x & 63) == 0) red[wid] = m;
  __syncthreads();
  m = fmaxf(fmaxf(red[0], red[1]), fmaxf(red[2], red[3]));
  __syncthreads();

  float s = 0.f;
  if (j0 < nvis) {
#pragma unroll
    for (int e = 0; e < 8; ++e) {
      float p = (j0 + e < nvis) ? __expf(v[e] - m) : 0.f;
      v[e] = p;
      s += p;
    }
  }
#pragma unroll
  for (int o = 32; o; o >>= 1) s += __shfl_xor(s, o);
  if ((threadIdx.x & 63) == 0) red[wid] = s;
  __syncthreads();
  s = red[0] + red[1] + red[2] + red[3];
  const float inv = 1.0f / s;

  if (j0 < capJ) {
    short8v o8;
#pragma unroll
    for (int e = 0; e < 8; ++e)
      o8[e] = (short)f2b((j0 + e < nvis) ? v[e] * inv : 0.f);
    *(short8v*)&SP[base + j0] = o8;
  }
}

// ---------------------------------------------------------------------------
extern "C" void kernel_launch(void* const* d_in, const int* in_sizes, int n_in,
                              void* d_out, int out_size, void* d_ws, size_t ws_size,
                              hipStream_t stream) {
  const float* x  = (const float*)d_in[0];
  const float* Wq = (const float*)d_in[1];
  const float* Wk = (const float*)d_in[2];
  const float* Wv = (const float*)d_in[3];
  float* out = (float*)d_out;

  const int B = 4, T = 2048, D = 1024;
  const int M = B * T;          // 8192
  const long TT = (long)T * T;  // 4 Mi elements

  char* ws = (char*)d_ws;
  u16* qk  = (u16*)(ws);                      // 32 MiB: [8192][2048], q|k
  u16* vt  = (u16*)(ws + (32l << 20));        // 16 MiB: [1024][8192] d-major
  u16* xb  = (u16*)(ws + (48l << 20));        // 16 MiB (dead after vts GEMM)
  u16* wqk = (u16*)(ws + (64l << 20));        //  4 MiB: [2048][1024]
  u16* wv  = (u16*)(ws + (68l << 20));        //  2 MiB
  u16* S   = (u16*)(ws + (72l << 20));        // 32 MiB: 4 x [2048][2048] bf16
  // peak: 104 MiB (ws is 256 MiB per r1 fill size)

  // fp32 -> bf16
  cvt_f32_bf16<<<2048, 256, 0, stream>>>(x, xb, (M * D) / 4);
  cvt_w3<<<3 * (D * D / 4) / 256, 256, 0, stream>>>(
      Wq, Wk, Wv, wqk, wqk + (long)D * D, wv, D * D / 4);

  // qk = x @ [Wq;Wk]^T  (8192 x 2048): grid 64x16 = 1024 blocks (2 rounds)
  gemm8<0, u16><<<dim3(M / 128, 2 * D / 128, 1), 256, 0, stream>>>(
      xb, D, 0, wqk, D, 0, qk, 2 * D, 0, D);

  // merged: vt = Wv @ x^T  AND  S_b = q_b k_b^T (1116 live blocks, backfill)
  gemm_vts<<<512 + 1024, 256, 0, stream>>>(xb, wv, qk, vt, S);

  // softmax in place (S -> P), all rows of all batches
  softmax_kernel<<<B * T, 256, 0, stream>>>(S, T);

  // O_b = P_b V_b = P_b (vt_b)^T, K capped per tile-row, pair-balanced
  gemm8<2, float><<<dim3(T / 128, D / 128, B), 256, 0, stream>>>(
      S, T, TT,
      vt, M, T,
      out, D, (long)T * D, T);
}